// Round 11
// baseline (194.639 us; speedup 1.0000x reference)
//
#include <hip/hip_runtime.h>
#include <hip/hip_fp16.h>
#include <math.h>

#define N_NODES 100000
#define N_EDGES 1600000
#define E_TOT (N_EDGES + N_NODES)   // self-loops injected as virtual edges
#define IN_FEAT 16
#define OUT_FEAT 16
#define HEADS 6
#define HF 96                 // HEADS*OUT_FEAT

// Bucketed-aggregate geometry:
#define NB 4096               // histogram bins in prep (4000 used)
#define NBA 4000              // active buckets (4000*25 = 100000 exactly)
#define NPB 25                // nodes per bucket
#define CAP 576               // per-bucket capacity: mean 416 incl self, +8 sigma
#define MAXDEG 64             // per-node slot capacity (Poisson(17): P(>=63) ~ 1e-18)
#define NBLK_PART 256         // partition blocks
#define NT_BLOCKS ((N_NODES * HEADS + 255) / 256)

// ---------------------------------------------------------------------------
// K1: prep = partition (blocks [0,NBLK_PART)) + node_transform (rest).
// Partition covers E_TOT (virtual self-loop edges e>=N_EDGES -> s=d=e-N_E).
// gcursor starts at 0 (memsetAsync) so its final value IS the bucket count.
// Transform branch also emits data_f16 (3.2 MB -> L2-resident gathers).
// spack[pos] = src | (d_local << 17)
// ---------------------------------------------------------------------------
__global__ void prep(const int* __restrict__ esrc,
                     const int* __restrict__ edst,
                     int* __restrict__ gcursor,
                     unsigned int* __restrict__ spack,
                     const float* __restrict__ data,
                     const float* __restrict__ W,
                     const float* __restrict__ att_src,
                     const float* __restrict__ att_dst,
                     float* __restrict__ a_src,
                     float* __restrict__ a_dst,
                     unsigned short* __restrict__ data_f16) {
    __shared__ int shmem[2 * NB];   // 32 KB

    if (blockIdx.x < NBLK_PART) {
        // ---------------- partition branch ----------------
        int* hist = shmem;
        int* base = shmem + NB;
        const int chunk = (E_TOT + NBLK_PART - 1) / NBLK_PART;   // 6641
        const int e0 = blockIdx.x * chunk;
        const int e1 = min(e0 + chunk, E_TOT);

        for (int j = threadIdx.x; j < NB; j += blockDim.x) hist[j] = 0;
        __syncthreads();
        for (int e = e0 + threadIdx.x; e < e1; e += blockDim.x) {
            int d = (e < N_EDGES) ? edst[e] : (e - N_EDGES);
            atomicAdd(&hist[d / NPB], 1);      // native int ds_add
        }
        __syncthreads();
        for (int j = threadIdx.x; j < NB; j += blockDim.x) {
            int c = hist[j];
            base[j] = c ? atomicAdd(&gcursor[j], c) : 0;
        }
        __syncthreads();
        for (int j = threadIdx.x; j < NB; j += blockDim.x) hist[j] = 0;
        __syncthreads();
        for (int e = e0 + threadIdx.x; e < e1; e += blockDim.x) {
            int s, d;
            if (e < N_EDGES) { s = esrc[e]; d = edst[e]; }
            else             { s = d = e - N_EDGES; }
            int b = d / NPB;
            int r = atomicAdd(&hist[b], 1);
            int pos = b * CAP + base[b] + r;
            if (pos < (b + 1) * CAP)           // statistically unreachable
                spack[pos] = (unsigned int)s | ((unsigned int)(d - b * NPB) << 17);
        }
    } else {
        // ---------------- node_transform branch ----------------
        float* sW  = (float*)shmem;            // 1536 floats
        float* sAs = sW + IN_FEAT * HF;        // 96
        float* sAd = sAs + HF;                 // 96
        for (int i = threadIdx.x; i < IN_FEAT * HF; i += blockDim.x) sW[i] = W[i];
        for (int i = threadIdx.x; i < HF; i += blockDim.x) { sAs[i] = att_src[i]; sAd[i] = att_dst[i]; }
        __syncthreads();

        int gid = (blockIdx.x - NBLK_PART) * blockDim.x + threadIdx.x;
        int n = gid / HEADS;
        int h = gid % HEADS;
        if (n >= N_NODES) return;

        float dv[IN_FEAT];
        const float4* dp = (const float4*)(data + (size_t)n * IN_FEAT);
#pragma unroll
        for (int q = 0; q < 4; q++) {
            float4 v = dp[q];
            dv[q*4+0] = v.x; dv[q*4+1] = v.y; dv[q*4+2] = v.z; dv[q*4+3] = v.w;
        }

        // emit f16 copy of the row (threads h=0..3 each pack 4 halves)
        if (h < 4) {
            unsigned int lo = (unsigned int)__half_as_ushort(__float2half_rn(dv[h*4+0]))
                            | ((unsigned int)__half_as_ushort(__float2half_rn(dv[h*4+1])) << 16);
            unsigned int hi = (unsigned int)__half_as_ushort(__float2half_rn(dv[h*4+2]))
                            | ((unsigned int)__half_as_ushort(__float2half_rn(dv[h*4+3])) << 16);
            uint2 pk; pk.x = lo; pk.y = hi;
            *(uint2*)(data_f16 + (size_t)n * IN_FEAT + h * 4) = pk;
        }

        float outv[OUT_FEAT];
#pragma unroll
        for (int fo = 0; fo < OUT_FEAT; fo++) outv[fo] = 0.f;
#pragma unroll
        for (int k = 0; k < IN_FEAT; k++) {
            float dk = dv[k];
            const float* wrow = &sW[k * HF + h * OUT_FEAT];
#pragma unroll
            for (int fo = 0; fo < OUT_FEAT; fo++) outv[fo] = fmaf(dk, wrow[fo], outv[fo]);
        }

        float as = 0.f, ad = 0.f;
#pragma unroll
        for (int fo = 0; fo < OUT_FEAT; fo++) {
            as = fmaf(outv[fo], sAs[h * OUT_FEAT + fo], as);
            ad = fmaf(outv[fo], sAd[h * OUT_FEAT + fo], ad);
        }
        a_src[n * HEADS + h] = as;
        a_dst[n * HEADS + h] = ad;
    }
}

// ---------------------------------------------------------------------------
// K2: bucket accumulate v4 — minimum passes, 3 barriers (was 8).
//  - single-pass binning into FIXED per-node slots olist[dl*64+r] (no count
//    pass, no serial prefix, no cursor copy — R10's 8-barrier chain was the
//    stall, not bytes or VALU)
//  - phase A: dynamic node->wave ticketing (kills inter-wave degree
//    imbalance); per edge the 6 exps are computed INLINE, redundantly on all
//    16 lanes of the slot (6 same-line a_src loads + ~36 VALU — VALUBusy had
//    60% headroom; removes the ex pass, its barrier, 9.2 KB exl, and the
//    per-edge ds_read dependency)
//  - phase B: dense per-node W transform from LDS wsn (W via L1)
// No fp atomics anywhere. LDS ~16.6 KB.
// ---------------------------------------------------------------------------
__global__ __launch_bounds__(256, 8)
void bucket_accumulate(const int* __restrict__ gcursor,
                       const unsigned int* __restrict__ spack,
                       const float* __restrict__ data,
                       const unsigned short* __restrict__ data_f16,
                       const float* __restrict__ a_src,
                       const float* __restrict__ a_dst,
                       const float* __restrict__ W,
                       const float* __restrict__ bias,
                       float* __restrict__ out) {
    const int b = blockIdx.x;
    const int n0 = b * NPB;                    // grid = NBA -> always nn == NPB
    __shared__ unsigned int olist[NPB * MAXDEG];   // 6.4 KB
    __shared__ float wsn_l[NPB * 100];             // 10 KB, pad stride 100
    __shared__ int cnt[NPB];
    __shared__ int nidx;

    const int tid  = threadIdx.x;
    const int lane = tid & 63;
    const int slot = lane >> 4;       // 4 edge-slots per wave
    const int f    = lane & 15;       // feature/k index

    int ecnt = gcursor[b];
    if (ecnt > CAP) ecnt = CAP;       // statistically unreachable

    for (int j = tid; j < NPB; j += 256) cnt[j] = 0;
    if (tid == 0) nidx = 0;
    __syncthreads();

    // ---- single-pass bin into fixed per-node slots ----
    for (int i = tid; i < ecnt; i += 256) {
        unsigned int p = spack[b * CAP + i];
        int dl = (int)(p >> 17);
        int r = atomicAdd(&cnt[dl], 1);
        if (r < MAXDEG)                // statistically unreachable guard
            olist[dl * MAXDEG + r] = p & 0x1FFFFu;
    }
    __syncthreads();

    // ---- phase A: dynamic node->wave assignment ----
    for (;;) {
        int my;
        if (lane == 0) my = atomicAdd(&nidx, 1);
        my = __builtin_amdgcn_readfirstlane(my);
        if (my >= NPB) break;
        const int n = n0 + my;

        float ad[HEADS];
#pragma unroll
        for (int h = 0; h < HEADS; h++) ad[h] = a_dst[n * HEADS + h];

        int T = cnt[my];
        if (T > MAXDEG) T = MAXDEG;
        const unsigned int* ol = olist + my * MAXDEG;

        float ws[HEADS], dn[HEADS];
#pragma unroll
        for (int h = 0; h < HEADS; h++) { ws[h] = 0.f; dn[h] = 0.f; }

        for (int t = slot; t < T; t += 4) {
            int s = (int)ol[t];
            float dv = __half2float(__ushort_as_half(data_f16[(size_t)s * IN_FEAT + f]));
#pragma unroll
            for (int h = 0; h < HEADS; h++) {
                float e = a_src[s * HEADS + h] + ad[h];   // same line across slot lanes
                e = e > 0.f ? e : 0.2f * e;               // leaky relu
                float ex = __expf(e);
                ws[h] = fmaf(dv, ex, ws[h]);
                dn[h] += ex;
            }
        }

        // butterfly over the 4 slots -> every lane holds totals
#pragma unroll
        for (int h = 0; h < HEADS; h++) {
            ws[h] += __shfl_xor(ws[h], 16);
            ws[h] += __shfl_xor(ws[h], 32);
            dn[h] += __shfl_xor(dn[h], 16);
            dn[h] += __shfl_xor(dn[h], 32);
        }

        if (slot == 0) {
            float cs = 0.f;
#pragma unroll
            for (int h = 0; h < HEADS; h++) {
                float wsn = ws[h] * __builtin_amdgcn_rcpf(dn[h] + 1e-16f);
                cs += wsn;
                wsn_l[my * 100 + h * 16 + f] = wsn;
            }
            if (f < 2) {                      // fused coord output
                float c = cs * (0.2f / 6.f);
                float key = data[(size_t)n * IN_FEAT + f];
                if (key == 1.0f)      c = 1.0f;
                else if (key == 0.0f) c = 0.0f;
                out[n * 2 + f] = c;
            }
        }
    }
    __syncthreads();

    // ---- phase B: dense per-node transform; W via L1 (6 KB, hot) ----
    const float sc = 1.0507009873554805f;
    const float al = 1.6732632423543772f;
    for (int task = tid; task < NPB * 16; task += 256) {
        int dl = task >> 4, fo = task & 15;
        float acc = 0.f;
#pragma unroll
        for (int h = 0; h < HEADS; h++) {
            const float* wr = wsn_l + dl * 100 + h * 16;
            const float* Wc = W + h * 16 + fo;
#pragma unroll
            for (int k = 0; k < IN_FEAT; k++)
                acc = fmaf(wr[k], Wc[k * HF], acc);
        }
        float v = acc * (1.f / 6.f) + bias[fo];
        v = v > 0.f ? sc * v : sc * al * (__expf(v) - 1.f);
        out[2 * N_NODES + (size_t)(n0 + dl) * OUT_FEAT + fo] = v;
    }
}

// ---------------------------------------------------------------------------
// Workspace layout (float offsets):
//   [0, 600000)            a_src    (N*6)
//   [600000, 1200000)      a_dst    (N*6)
//   [1200000, 1204096)     gcursor  (NB ints, memsetAsync to 0 each launch)
//   [1204096, 3563392)     spack    (NB*CAP uints = 9.4 MB)
//   [3563392, 4363392)     data_f16 (N*16 halves = 3.2 MB)
// ---------------------------------------------------------------------------
extern "C" void kernel_launch(void* const* d_in, const int* in_sizes, int n_in,
                              void* d_out, int out_size, void* d_ws, size_t ws_size,
                              hipStream_t stream) {
    const float* data    = (const float*)d_in[0];
    const int*   eidx    = (const int*)d_in[1];      // int32 on device
    const float* W       = (const float*)d_in[2];
    const float* att_src = (const float*)d_in[3];
    const float* att_dst = (const float*)d_in[4];
    const float* bias    = (const float*)d_in[5];
    float*       out     = (float*)d_out;
    float*       ws      = (float*)d_ws;

    float*          a_src    = ws;
    float*          a_dst    = ws + 600000;
    int*            gcursor  = (int*)(ws + 1200000);
    unsigned int*   spack    = (unsigned int*)(ws + 1204096);
    unsigned short* data_f16 = (unsigned short*)(ws + 3563392);

    hipMemsetAsync(gcursor, 0, NB * sizeof(int), stream);

    prep<<<NBLK_PART + NT_BLOCKS, 256, 0, stream>>>(
        eidx, eidx + N_EDGES, gcursor, spack,
        data, W, att_src, att_dst, a_src, a_dst, data_f16);

    bucket_accumulate<<<NBA, 256, 0, stream>>>(
        gcursor, spack, data, data_f16, a_src, a_dst, W, bias, out);
}

// Round 12
// 156.377 us; speedup vs baseline: 1.2447x; 1.2447x over previous
//
#include <hip/hip_runtime.h>
#include <hip/hip_fp16.h>
#include <math.h>

#define N_NODES 100000
#define N_EDGES 1600000
#define E_TOT (N_EDGES + N_NODES)   // self-loops injected as virtual edges
#define IN_FEAT 16
#define OUT_FEAT 16
#define HEADS 6
#define HF 96                 // HEADS*OUT_FEAT

// Bucketed-aggregate geometry:
#define NB 4096               // histogram bins in prep (4000 used)
#define NBA 4000              // active buckets (4000*25 = 100000 exactly)
#define NPB 25                // nodes per bucket
#define CAP 576               // per-bucket capacity: mean 416 incl self, +8 sigma
#define MAXDEG 64             // per-node slot capacity (Poisson(17): P(>=63) ~ 1e-18)
#define NBLK_PART 256         // partition blocks
#define NT_BLOCKS ((N_NODES * HEADS + 255) / 256)

// ---------------------------------------------------------------------------
// K1: prep = partition (blocks [0,NBLK_PART)) + node_transform (rest).
// Partition covers E_TOT (virtual self-loop edges e>=N_EDGES -> s=d=e-N_E).
// gcursor starts at 0 (memsetAsync) so its final value IS the bucket count.
// Transform branch also emits data_f16 (3.2 MB -> L2-resident gathers).
// spack[pos] = src | (d_local << 17)
// ---------------------------------------------------------------------------
__global__ void prep(const int* __restrict__ esrc,
                     const int* __restrict__ edst,
                     int* __restrict__ gcursor,
                     unsigned int* __restrict__ spack,
                     const float* __restrict__ data,
                     const float* __restrict__ W,
                     const float* __restrict__ att_src,
                     const float* __restrict__ att_dst,
                     float* __restrict__ a_src,
                     float* __restrict__ a_dst,
                     unsigned short* __restrict__ data_f16) {
    __shared__ int shmem[2 * NB];   // 32 KB

    if (blockIdx.x < NBLK_PART) {
        // ---------------- partition branch ----------------
        int* hist = shmem;
        int* base = shmem + NB;
        const int chunk = (E_TOT + NBLK_PART - 1) / NBLK_PART;   // 6641
        const int e0 = blockIdx.x * chunk;
        const int e1 = min(e0 + chunk, E_TOT);

        for (int j = threadIdx.x; j < NB; j += blockDim.x) hist[j] = 0;
        __syncthreads();
        for (int e = e0 + threadIdx.x; e < e1; e += blockDim.x) {
            int d = (e < N_EDGES) ? edst[e] : (e - N_EDGES);
            atomicAdd(&hist[d / NPB], 1);      // native int ds_add
        }
        __syncthreads();
        for (int j = threadIdx.x; j < NB; j += blockDim.x) {
            int c = hist[j];
            base[j] = c ? atomicAdd(&gcursor[j], c) : 0;
        }
        __syncthreads();
        for (int j = threadIdx.x; j < NB; j += blockDim.x) hist[j] = 0;
        __syncthreads();
        for (int e = e0 + threadIdx.x; e < e1; e += blockDim.x) {
            int s, d;
            if (e < N_EDGES) { s = esrc[e]; d = edst[e]; }
            else             { s = d = e - N_EDGES; }
            int b = d / NPB;
            int r = atomicAdd(&hist[b], 1);
            int pos = b * CAP + base[b] + r;
            if (pos < (b + 1) * CAP)           // statistically unreachable
                spack[pos] = (unsigned int)s | ((unsigned int)(d - b * NPB) << 17);
        }
    } else {
        // ---------------- node_transform branch ----------------
        float* sW  = (float*)shmem;            // 1536 floats
        float* sAs = sW + IN_FEAT * HF;        // 96
        float* sAd = sAs + HF;                 // 96
        for (int i = threadIdx.x; i < IN_FEAT * HF; i += blockDim.x) sW[i] = W[i];
        for (int i = threadIdx.x; i < HF; i += blockDim.x) { sAs[i] = att_src[i]; sAd[i] = att_dst[i]; }
        __syncthreads();

        int gid = (blockIdx.x - NBLK_PART) * blockDim.x + threadIdx.x;
        int n = gid / HEADS;
        int h = gid % HEADS;
        if (n >= N_NODES) return;

        float dv[IN_FEAT];
        const float4* dp = (const float4*)(data + (size_t)n * IN_FEAT);
#pragma unroll
        for (int q = 0; q < 4; q++) {
            float4 v = dp[q];
            dv[q*4+0] = v.x; dv[q*4+1] = v.y; dv[q*4+2] = v.z; dv[q*4+3] = v.w;
        }

        // emit f16 copy of the row (threads h=0..3 each pack 4 halves)
        if (h < 4) {
            unsigned int lo = (unsigned int)__half_as_ushort(__float2half_rn(dv[h*4+0]))
                            | ((unsigned int)__half_as_ushort(__float2half_rn(dv[h*4+1])) << 16);
            unsigned int hi = (unsigned int)__half_as_ushort(__float2half_rn(dv[h*4+2]))
                            | ((unsigned int)__half_as_ushort(__float2half_rn(dv[h*4+3])) << 16);
            uint2 pk; pk.x = lo; pk.y = hi;
            *(uint2*)(data_f16 + (size_t)n * IN_FEAT + h * 4) = pk;
        }

        float outv[OUT_FEAT];
#pragma unroll
        for (int fo = 0; fo < OUT_FEAT; fo++) outv[fo] = 0.f;
#pragma unroll
        for (int k = 0; k < IN_FEAT; k++) {
            float dk = dv[k];
            const float* wrow = &sW[k * HF + h * OUT_FEAT];
#pragma unroll
            for (int fo = 0; fo < OUT_FEAT; fo++) outv[fo] = fmaf(dk, wrow[fo], outv[fo]);
        }

        float as = 0.f, ad = 0.f;
#pragma unroll
        for (int fo = 0; fo < OUT_FEAT; fo++) {
            as = fmaf(outv[fo], sAs[h * OUT_FEAT + fo], as);
            ad = fmaf(outv[fo], sAd[h * OUT_FEAT + fo], ad);
        }
        a_src[n * HEADS + h] = as;
        a_dst[n * HEADS + h] = ad;
    }
}

// ---------------------------------------------------------------------------
// K2: bucket accumulate v4.1 — same structure as R11 (3 barriers, single-pass
// fixed-slot binning, dynamic node ticketing, inline exp), but with the
// launch-bounds bug fixed: R11's (256, 8) meant 8 WAVES PER EU (not 8
// blocks/CU), capping VGPR at 64 -> allocator squeezed to 32 and SPILLED the
// 18 accumulator floats to scratch: 184 MB of scratch writes + 174 MB extra
// fetch per dispatch. (256, 4) gives a 128-VGPR budget (kernel needs ~70-80,
// no spill) at 16 waves/CU.
// ---------------------------------------------------------------------------
__global__ __launch_bounds__(256, 4)
void bucket_accumulate(const int* __restrict__ gcursor,
                       const unsigned int* __restrict__ spack,
                       const float* __restrict__ data,
                       const unsigned short* __restrict__ data_f16,
                       const float* __restrict__ a_src,
                       const float* __restrict__ a_dst,
                       const float* __restrict__ W,
                       const float* __restrict__ bias,
                       float* __restrict__ out) {
    const int b = blockIdx.x;
    const int n0 = b * NPB;                    // grid = NBA -> always nn == NPB
    __shared__ unsigned int olist[NPB * MAXDEG];   // 6.4 KB
    __shared__ float wsn_l[NPB * 100];             // 10 KB, pad stride 100
    __shared__ int cnt[NPB];
    __shared__ int nidx;

    const int tid  = threadIdx.x;
    const int lane = tid & 63;
    const int slot = lane >> 4;       // 4 edge-slots per wave
    const int f    = lane & 15;       // feature/k index

    int ecnt = gcursor[b];
    if (ecnt > CAP) ecnt = CAP;       // statistically unreachable

    for (int j = tid; j < NPB; j += 256) cnt[j] = 0;
    if (tid == 0) nidx = 0;
    __syncthreads();

    // ---- single-pass bin into fixed per-node slots ----
    for (int i = tid; i < ecnt; i += 256) {
        unsigned int p = spack[b * CAP + i];
        int dl = (int)(p >> 17);
        int r = atomicAdd(&cnt[dl], 1);
        if (r < MAXDEG)                // statistically unreachable guard
            olist[dl * MAXDEG + r] = p & 0x1FFFFu;
    }
    __syncthreads();

    // ---- phase A: dynamic node->wave assignment ----
    for (;;) {
        int my;
        if (lane == 0) my = atomicAdd(&nidx, 1);
        my = __builtin_amdgcn_readfirstlane(my);
        if (my >= NPB) break;
        const int n = n0 + my;

        float ad[HEADS];
#pragma unroll
        for (int h = 0; h < HEADS; h++) ad[h] = a_dst[n * HEADS + h];

        int T = cnt[my];
        if (T > MAXDEG) T = MAXDEG;
        const unsigned int* ol = olist + my * MAXDEG;

        float ws[HEADS], dn[HEADS];
#pragma unroll
        for (int h = 0; h < HEADS; h++) { ws[h] = 0.f; dn[h] = 0.f; }

        for (int t = slot; t < T; t += 4) {
            int s = (int)ol[t];
            float dv = __half2float(__ushort_as_half(data_f16[(size_t)s * IN_FEAT + f]));
#pragma unroll
            for (int h = 0; h < HEADS; h++) {
                float e = a_src[s * HEADS + h] + ad[h];   // same line across slot lanes
                e = e > 0.f ? e : 0.2f * e;               // leaky relu
                float ex = __expf(e);
                ws[h] = fmaf(dv, ex, ws[h]);
                dn[h] += ex;
            }
        }

        // butterfly over the 4 slots -> every lane holds totals
#pragma unroll
        for (int h = 0; h < HEADS; h++) {
            ws[h] += __shfl_xor(ws[h], 16);
            ws[h] += __shfl_xor(ws[h], 32);
            dn[h] += __shfl_xor(dn[h], 16);
            dn[h] += __shfl_xor(dn[h], 32);
        }

        if (slot == 0) {
            float cs = 0.f;
#pragma unroll
            for (int h = 0; h < HEADS; h++) {
                float wsn = ws[h] * __builtin_amdgcn_rcpf(dn[h] + 1e-16f);
                cs += wsn;
                wsn_l[my * 100 + h * 16 + f] = wsn;
            }
            if (f < 2) {                      // fused coord output
                float c = cs * (0.2f / 6.f);
                float key = data[(size_t)n * IN_FEAT + f];
                if (key == 1.0f)      c = 1.0f;
                else if (key == 0.0f) c = 0.0f;
                out[n * 2 + f] = c;
            }
        }
    }
    __syncthreads();

    // ---- phase B: dense per-node transform; W via L1 (6 KB, hot) ----
    const float sc = 1.0507009873554805f;
    const float al = 1.6732632423543772f;
    for (int task = tid; task < NPB * 16; task += 256) {
        int dl = task >> 4, fo = task & 15;
        float acc = 0.f;
#pragma unroll
        for (int h = 0; h < HEADS; h++) {
            const float* wr = wsn_l + dl * 100 + h * 16;
            const float* Wc = W + h * 16 + fo;
#pragma unroll
            for (int k = 0; k < IN_FEAT; k++)
                acc = fmaf(wr[k], Wc[k * HF], acc);
        }
        float v = acc * (1.f / 6.f) + bias[fo];
        v = v > 0.f ? sc * v : sc * al * (__expf(v) - 1.f);
        out[2 * N_NODES + (size_t)(n0 + dl) * OUT_FEAT + fo] = v;
    }
}

// ---------------------------------------------------------------------------
// Workspace layout (float offsets):
//   [0, 600000)            a_src    (N*6)
//   [600000, 1200000)      a_dst    (N*6)
//   [1200000, 1204096)     gcursor  (NB ints, memsetAsync to 0 each launch)
//   [1204096, 3563392)     spack    (NB*CAP uints = 9.4 MB)
//   [3563392, 4363392)     data_f16 (N*16 halves = 3.2 MB)
// ---------------------------------------------------------------------------
extern "C" void kernel_launch(void* const* d_in, const int* in_sizes, int n_in,
                              void* d_out, int out_size, void* d_ws, size_t ws_size,
                              hipStream_t stream) {
    const float* data    = (const float*)d_in[0];
    const int*   eidx    = (const int*)d_in[1];      // int32 on device
    const float* W       = (const float*)d_in[2];
    const float* att_src = (const float*)d_in[3];
    const float* att_dst = (const float*)d_in[4];
    const float* bias    = (const float*)d_in[5];
    float*       out     = (float*)d_out;
    float*       ws      = (float*)d_ws;

    float*          a_src    = ws;
    float*          a_dst    = ws + 600000;
    int*            gcursor  = (int*)(ws + 1200000);
    unsigned int*   spack    = (unsigned int*)(ws + 1204096);
    unsigned short* data_f16 = (unsigned short*)(ws + 3563392);

    hipMemsetAsync(gcursor, 0, NB * sizeof(int), stream);

    prep<<<NBLK_PART + NT_BLOCKS, 256, 0, stream>>>(
        eidx, eidx + N_EDGES, gcursor, spack,
        data, W, att_src, att_dst, a_src, a_dst, data_f16);

    bucket_accumulate<<<NBA, 256, 0, stream>>>(
        gcursor, spack, data, data_f16, a_src, a_dst, W, bias, out);
}